// Round 4
// baseline (269.321 us; speedup 1.0000x reference)
//
#include <hip/hip_runtime.h>

#define NROWS 8192
#define BBND  32
#define CBND  512
#define JQ    2048            // j-range per block
#define JSTEP 32
#define NTQ   (JQ / JSTEP)    // 64 iters
#define ABUFB 4096            // A LDS buffer bytes (64 rows x 64B)
#define BBUFB 32768           // B LDS buffer bytes (512 rows x 64B)

typedef unsigned short u16;
typedef unsigned int   u32;
typedef __bf16 bf16x8 __attribute__((ext_vector_type(8)));
typedef float  f32x4  __attribute__((ext_vector_type(4)));
typedef float  f32x16 __attribute__((ext_vector_type(16)));
typedef u32    u32x4  __attribute__((ext_vector_type(4)));
typedef u32    u32x2  __attribute__((ext_vector_type(2)));

#define ZERO16 (f32x16){0.f,0.f,0.f,0.f,0.f,0.f,0.f,0.f,0.f,0.f,0.f,0.f,0.f,0.f,0.f,0.f}

static __device__ inline u16 f2bf(float f) {
    unsigned u = __builtin_bit_cast(unsigned, f);
    unsigned r = (u + 0x7FFFu + ((u >> 16) & 1u)) >> 16;
    return (u16)r;
}

static __device__ inline float pow14(float base) {
    return __builtin_amdgcn_exp2f(1.4f * __builtin_amdgcn_logf(base));
}

static __device__ inline float adj_eval(float dot, float sij) {
    float x = fabsf(2.f * dot - sij);
    float base = fmaxf(1.f - x * (1.f / 32.f), 0.f);
    return pow14(base);
}

static __device__ inline float sigmoidf_fast(float v) {
    float e = __builtin_amdgcn_exp2f(-1.44269504f * v);
    return 1.f / (1.f + e);
}

static __device__ inline u32 cvtpk(float a, float b) {
    u32 r;
    asm("v_cvt_pk_bf16_f32 %0, %1, %2" : "=v"(r) : "v"(a), "v"(b));
    return r;
}

static __device__ inline f32x4 MFMA16(bf16x8 a, bf16x8 b, f32x4 c) {
    return __builtin_amdgcn_mfma_f32_16x16x32_bf16(a, b, c, 0, 0, 0);
}
static __device__ inline f32x16 MFMA32(bf16x8 a, bf16x8 b, f32x16 c) {
    return __builtin_amdgcn_mfma_f32_32x32x16_bf16(a, b, c, 0, 0, 0);
}

// ---------------- prep: row sums of bbn + bf16 copy ----------------
__global__ __launch_bounds__(256) void k_prep_rows(const float* __restrict__ bbn,
                                                   float* __restrict__ s,
                                                   u16* __restrict__ bbn_bf) {
    int i = blockIdx.x * 256 + threadIdx.x;
    if (i >= NROWS) return;
    const f32x4* row = reinterpret_cast<const f32x4*>(bbn + i * BBND);
    float sum = 0.f;
    u16* dst = bbn_bf + i * BBND;
#pragma unroll
    for (int q = 0; q < 8; ++q) {
        f32x4 v = row[q];
#pragma unroll
        for (int e = 0; e < 4; ++e) {
            sum += v[e];
            dst[q * 4 + e] = f2bf(v[e]);
        }
    }
    s[i] = sum;
}

// ---------------- prep: W transpose -> bf16 ----------------
__global__ __launch_bounds__(256) void k_prep_wt(const float* __restrict__ W,
                                                 u16* __restrict__ WT) {
    int idx = blockIdx.x * 256 + threadIdx.x;   // over 512*512
    int c = idx >> 9, k = idx & 511;
    WT[idx] = f2bf(W[k * CBND + c]);            // WT[c][k]
}

// ---------------- degree: d_i = sum_j adj_ij ; dinv = rsqrt(d+eps) ----------------
__global__ __launch_bounds__(512) void k_deg(const u16* __restrict__ bbn_bf,
                                             const float* __restrict__ s,
                                             float* __restrict__ dinv) {
    __shared__ float part[8][16];
    int ibase = blockIdx.x * 16;
    int tid = threadIdx.x;
    int w = tid >> 6, l = tid & 63, lg = l >> 4, lr = l & 15;

    bf16x8 afrag = *reinterpret_cast<const bf16x8*>(bbn_bf + (ibase + lr) * BBND + lg * 8);
    float si[4];
#pragma unroll
    for (int r = 0; r < 4; ++r) si[r] = s[ibase + lg * 4 + r];

    float dacc[4] = {0.f, 0.f, 0.f, 0.f};
    int j0 = w * (NROWS / 8);
    for (int jt = 0; jt < NROWS / 8; jt += 16) {
        int jb = j0 + jt;
        bf16x8 bfrag = *reinterpret_cast<const bf16x8*>(bbn_bf + (jb + lr) * BBND + lg * 8);
        f32x4 dot = MFMA16(afrag, bfrag, (f32x4){0.f, 0.f, 0.f, 0.f});
        float sj = s[jb + lr];
#pragma unroll
        for (int r = 0; r < 4; ++r) dacc[r] += adj_eval(dot[r], si[r] + sj);
    }
#pragma unroll
    for (int off = 1; off < 16; off <<= 1)
#pragma unroll
        for (int r = 0; r < 4; ++r) dacc[r] += __shfl_xor(dacc[r], off, 64);

    if (lr == 0) {
#pragma unroll
        for (int r = 0; r < 4; ++r) part[w][lg * 4 + r] = dacc[r];
    }
    __syncthreads();
    if (tid < 16) {
        float d = 0.f;
#pragma unroll
        for (int q = 0; q < 8; ++q) d += part[q][tid];
        dinv[ibase + tid] = rsqrtf(d + 1e-8f);
    }
}

// ---------------- fc: gT[c][j] = dinv_j * (cbn@W + b)[j][c], bf16 ----------------
__global__ __launch_bounds__(256) void k_fc(const float* __restrict__ cbn,
                                            const u16* __restrict__ WT,
                                            const float* __restrict__ bvec,
                                            const float* __restrict__ dinv,
                                            u16* __restrict__ gT) {
    int bid = blockIdx.x;
    int cb = bid & 7, jb = bid >> 3;
    int tid = threadIdx.x, w = tid >> 6, l = tid & 63, lg = l >> 4, lr = l & 15;
    int crow = cb * 64 + w * 16;
    int jcol = jb * 64;

    f32x4 acc[4];
#pragma unroll
    for (int f = 0; f < 4; ++f) acc[f] = (f32x4){0.f, 0.f, 0.f, 0.f};

    for (int k0 = 0; k0 < CBND; k0 += 32) {
        bf16x8 afrag = *reinterpret_cast<const bf16x8*>(WT + (crow + lr) * CBND + k0 + lg * 8);
#pragma unroll
        for (int f = 0; f < 4; ++f) {
            const float* src = cbn + (jcol + f * 16 + lr) * CBND + k0 + lg * 8;
            f32x4 v0 = *reinterpret_cast<const f32x4*>(src);
            f32x4 v1 = *reinterpret_cast<const f32x4*>(src + 4);
            bf16x8 bfrag;
#pragma unroll
            for (int e = 0; e < 4; ++e) { bfrag[e] = (__bf16)v0[e]; bfrag[e + 4] = (__bf16)v1[e]; }
            acc[f] = MFMA16(afrag, bfrag, acc[f]);
        }
    }
#pragma unroll
    for (int f = 0; f < 4; ++f) {
#pragma unroll
        for (int r = 0; r < 4; ++r) {
            int c = crow + lg * 4 + r;
            int j = jcol + f * 16 + lr;
            float val = acc[f][r] + bvec[c];
            gT[c * NROWS + j] = f2bf(val * dinv[j]);
        }
    }
}

// ---------------- conv: atomic-accumulate sum_j adj_ij * gT[:,j] into out ----------------
// Grid 512 = 128 i-tiles x 4 j-quarters. Block 512 thr (8 waves), tile 64i x 512c,
// j-quarter 2048, j-step 32. Wave = 32i x 128c via MFMA 32x32x16 (2 iw x 4 cw).
// adj generated exactly once per (i,j). One barrier/iter, dbuf LDS, XOR swizzle
// (slot ^= row&3 on 64B rows) keeps every LDS access at the 8-cycle minimum.

#define GEN_STAGE(T, WB) { \
    const char* srcp = gTb + src0 + (T) * 64; \
    u32x4 s0 = *reinterpret_cast<const u32x4*>(srcp); \
    u32x4 s1 = *reinterpret_cast<const u32x4*>(srcp + 0x200000); \
    u32x4 s2 = *reinterpret_cast<const u32x4*>(srcp + 0x400000); \
    u32x4 s3 = *reinterpret_cast<const u32x4*>(srcp + 0x600000); \
    int jg = jbase + (T) * JSTEP + jh2 * 16; \
    bf16x8 fJ = *reinterpret_cast<const bf16x8*>(bbn_bf + (jg + lr) * BBND + lg * 8); \
    f32x4 sj = *reinterpret_cast<const f32x4*>(s + jg + lg * 4); \
    f32x4 dot = MFMA16(fJ, fragI, (f32x4){0.f, 0.f, 0.f, 0.f}); \
    u32 p0 = cvtpk(adj_eval(dot[0], si + sj[0]), adj_eval(dot[1], si + sj[1])); \
    u32 p1 = cvtpk(adj_eval(dot[2], si + sj[2]), adj_eval(dot[3], si + sj[3])); \
    char* Bw = Bb + (WB) * BBUFB; \
    *reinterpret_cast<u32x4*>(Bw + dst0)         = s0; \
    *reinterpret_cast<u32x4*>(Bw + dst0 + 8192)  = s1; \
    *reinterpret_cast<u32x4*>(Bw + dst0 + 16384) = s2; \
    *reinterpret_cast<u32x4*>(Bw + dst0 + 24576) = s3; \
    *reinterpret_cast<u32x2*>(Ab + (WB) * ABUFB + gw) = (u32x2){p0, p1}; \
}

#define CONV_BODY(T, RB, WB) { \
    __syncthreads(); \
    if ((T) + 1 < NTQ) GEN_STAGE((T) + 1, WB); \
    const char* Ar = Ab + (RB) * ABUFB; \
    const char* Br = Bb + (RB) * BBUFB; \
    bf16x8 A0 = *reinterpret_cast<const bf16x8*>(Ar + aoff0); \
    bf16x8 A1 = *reinterpret_cast<const bf16x8*>(Ar + aoff1); \
    bf16x8 B00 = *reinterpret_cast<const bf16x8*>(Br + boff0); \
    bf16x8 B01 = *reinterpret_cast<const bf16x8*>(Br + boff0 + 2048); \
    bf16x8 B02 = *reinterpret_cast<const bf16x8*>(Br + boff0 + 4096); \
    bf16x8 B03 = *reinterpret_cast<const bf16x8*>(Br + boff0 + 6144); \
    acc0 = MFMA32(A0, B00, acc0); \
    acc1 = MFMA32(A0, B01, acc1); \
    acc2 = MFMA32(A0, B02, acc2); \
    acc3 = MFMA32(A0, B03, acc3); \
    bf16x8 B10 = *reinterpret_cast<const bf16x8*>(Br + boff1); \
    bf16x8 B11 = *reinterpret_cast<const bf16x8*>(Br + boff1 + 2048); \
    bf16x8 B12 = *reinterpret_cast<const bf16x8*>(Br + boff1 + 4096); \
    bf16x8 B13 = *reinterpret_cast<const bf16x8*>(Br + boff1 + 6144); \
    acc0 = MFMA32(A1, B10, acc0); \
    acc1 = MFMA32(A1, B11, acc1); \
    acc2 = MFMA32(A1, B12, acc2); \
    acc3 = MFMA32(A1, B13, acc3); \
}

#define EPI(ACC, CB) { \
    _Pragma("unroll") \
    for (int reg = 0; reg < 16; ++reg) { \
        int rowD = (reg & 3) + 8 * (reg >> 2) + 4 * lh; \
        unsafeAtomicAdd(out + (long)(ibase + iw * 32 + rowD) * CBND + cw * 128 + (CB) * 32 + l31, ACC[reg]); \
    } \
}

__global__ __launch_bounds__(512, 4) void k_conv(const u16* __restrict__ bbn_bf,
                                                 const float* __restrict__ s,
                                                 const u16* __restrict__ gT,
                                                 float* __restrict__ out) {
    __shared__ __align__(16) u16 Alds[2][64 * 32];
    __shared__ __align__(16) u16 Blds[2][512 * 32];

    int bx = blockIdx.x;
    int xcd = bx & 7, grp = bx >> 3;
    int jq = xcd >> 1;                 // XCD pair shares a 2MB gT j-slice (L2-fit)
    int it = grp + 64 * (xcd & 1);     // 0..127
    int ibase = it * 64;
    int jbase = jq * JQ;

    int tid = threadIdx.x;
    int w = tid >> 6, l = tid & 63;
    int lr = l & 15, lg = l >> 4, l31 = l & 31, lh = l >> 5;
    int iw = w & 1, cw = w >> 1;       // acc wave tile: 32i x 128c
    int iqg = w & 3, jh2 = w >> 2;     // gen wave tile: 16i x 16j

    // gen hoists
    bf16x8 fragI = *reinterpret_cast<const bf16x8*>(bbn_bf + (ibase + iqg * 16 + lr) * BBND + lg * 8);
    float si = s[ibase + iqg * 16 + lr];

    char* Ab = (char*)&Alds[0][0];
    char* Bb = (char*)&Blds[0][0];
    const char* gTb = (const char*)gT;

    // stage lane constants: pass p covers rows cA + p*128, logical slot j8=l&3
    int cA = w * 16 + (l >> 2);
    int j8 = l & 3;
    int src0 = cA * 16384 + jbase * 2 + j8 * 16;            // + p*0x200000 + T*64
    int phys_st = j8 ^ ((l >> 2) & 3);                      // cA&3 == (l>>2)&3
    int dst0 = cA * 64 + (phys_st << 4);                    // + p*8192

    // acc fragment addrs (XOR swizzle slot^=(row&3) on 64B rows)
    int arow = iw * 32 + l31;
    int aoff0 = arow * 64 + (((lh)     ^ (arow & 3)) << 4);
    int aoff1 = arow * 64 + (((2 + lh) ^ (arow & 3)) << 4);
    int brow = cw * 128 + l31;                              // cb adds 32 rows = +2048B
    int boff0 = brow * 64 + (((lh)     ^ (brow & 3)) << 4);
    int boff1 = brow * 64 + (((2 + lh) ^ (brow & 3)) << 4);

    // gen write addr
    int grow = iqg * 16 + lr;
    int gw = grow * 64 + ((((jh2 * 2) + (lg >> 1)) ^ (grow & 3)) << 4) + (lg & 1) * 8;

    f32x16 acc0 = ZERO16, acc1 = ZERO16, acc2 = ZERO16, acc3 = ZERO16;

    GEN_STAGE(0, 0);

    for (int t2 = 0; t2 < NTQ; t2 += 2) {
        CONV_BODY(t2, 0, 1);
        CONV_BODY(t2 + 1, 1, 0);
    }

    EPI(acc0, 0);
    EPI(acc1, 1);
    EPI(acc2, 2);
    EPI(acc3, 3);
}

// ---------------- sigmoid epilogue: out = sigmoid(dinv_i * out), in place ----------------
__global__ __launch_bounds__(256) void k_sig(const float* __restrict__ dinv,
                                             float* __restrict__ out) {
    int idx = blockIdx.x * 256 + threadIdx.x;   // f32x4 index; 1,048,576 total
    float di = dinv[idx >> 7];
    f32x4 v = *reinterpret_cast<const f32x4*>(out + idx * 4);
#pragma unroll
    for (int e = 0; e < 4; ++e) v[e] = sigmoidf_fast(v[e] * di);
    *reinterpret_cast<f32x4*>(out + idx * 4) = v;
}

extern "C" void kernel_launch(void* const* d_in, const int* in_sizes, int n_in,
                              void* d_out, int out_size, void* d_ws, size_t ws_size,
                              hipStream_t stream) {
    const float* bbn = (const float*)d_in[0];   // [8192,32]
    const float* cbn = (const float*)d_in[1];   // [8192,512]
    const float* W   = (const float*)d_in[2];   // [512,512]
    const float* b   = (const float*)d_in[3];   // [512]
    float* out = (float*)d_out;                 // [8192,512] f32

    char* ws = (char*)d_ws;
    float* s      = (float*)ws;  ws += NROWS * 4;
    float* dinv   = (float*)ws;  ws += NROWS * 4;
    u16* bbn_bf   = (u16*)ws;    ws += NROWS * BBND * 2;
    u16* WT       = (u16*)ws;    ws += CBND * CBND * 2;
    u16* gT       = (u16*)ws;    ws += CBND * NROWS * 2;

    hipMemsetAsync(d_out, 0, (size_t)out_size * sizeof(float), stream);
    k_prep_rows<<<NROWS / 256, 256, 0, stream>>>(bbn, s, bbn_bf);
    k_prep_wt<<<(CBND * CBND) / 256, 256, 0, stream>>>(W, WT);
    k_deg<<<NROWS / 16, 512, 0, stream>>>(bbn_bf, s, dinv);
    k_fc<<<(NROWS / 64) * (CBND / 64), 256, 0, stream>>>(cbn, WT, b, dinv, gT);
    k_conv<<<(NROWS / 64) * 4, 512, 0, stream>>>(bbn_bf, s, gT, out);
    k_sig<<<(NROWS * CBND / 4) / 256, 256, 0, stream>>>(dinv, out);
}